// Round 4
// baseline (302.549 us; speedup 1.0000x reference)
//
#include <hip/hip_runtime.h>

typedef unsigned short u16;
typedef unsigned int u32;
typedef __attribute__((ext_vector_type(8))) short short8;
typedef __attribute__((ext_vector_type(4))) float fx4;

#define LOG2E 1.44269504088896340736f

__device__ __forceinline__ u16 f2bf(float f) {
    unsigned int u = __float_as_uint(f);
    u += 0x7fffu + ((u >> 16) & 1u);
    return (u16)(u >> 16);
}

__device__ __forceinline__ float bf2f(u16 v) {
    u32 u = ((u32)v) << 16;
    return __uint_as_float(u);
}

// pack two fp32 -> two truncated bf16 in one u32 (v_perm_b32)
__device__ __forceinline__ u32 pack_bf2(float lo, float hi) {
    return __builtin_amdgcn_perm(__float_as_uint(hi), __float_as_uint(lo), 0x07060302u);
}

__device__ __forceinline__ float fast_exp2(float x) {
#if __has_builtin(__builtin_amdgcn_exp2f)
    return __builtin_amdgcn_exp2f(x);
#else
    return exp2f(x);
#endif
}

__device__ __forceinline__ fx4 mfma16(short8 a, short8 b, fx4 c) {
    return __builtin_amdgcn_mfma_f32_16x16x32_bf16(a, b, c, 0, 0, 0);
}

__device__ __forceinline__ void gload_lds16(const u16* g, u16* l) {
    __builtin_amdgcn_global_load_lds(
        (const __attribute__((address_space(1))) void*)g,
        (__attribute__((address_space(3))) void*)l, 16, 0, 0);
}

// ---------------------------------------------------------------------------
// LayerNorm: x (8192 x 1024) -> yb (bf16: GEMM input AND residual).
// One wave per row (4 rows/block): shuffle-only reduction, no LDS/barriers.
// ---------------------------------------------------------------------------
__global__ __launch_bounds__(256) void ln_kernel(
    const float* __restrict__ x, const float* __restrict__ gamma,
    const float* __restrict__ beta, u16* __restrict__ yb) {
    int wave = threadIdx.x >> 6, lane = threadIdx.x & 63;
    int row = (blockIdx.x << 2) + wave;
    const float* xr = x + ((size_t)row << 10);
    float4 v[4];
    float s = 0.0f, sq = 0.0f;
#pragma unroll
    for (int i = 0; i < 4; ++i) {
        v[i] = *(const float4*)(xr + (i << 8) + (lane << 2));
        s  += v[i].x + v[i].y + v[i].z + v[i].w;
        sq += v[i].x * v[i].x + v[i].y * v[i].y + v[i].z * v[i].z + v[i].w * v[i].w;
    }
#pragma unroll
    for (int o = 32; o > 0; o >>= 1) {
        s  += __shfl_xor(s, o, 64);
        sq += __shfl_xor(sq, o, 64);
    }
    float mean = s * (1.0f / 1024.0f);
    float var  = sq * (1.0f / 1024.0f) - mean * mean;
    float rstd = rsqrtf(var + 1e-3f);
#pragma unroll
    for (int i = 0; i < 4; ++i) {
        int off = (i << 8) + (lane << 2);
        float4 g  = *(const float4*)(gamma + off);
        float4 bb = *(const float4*)(beta + off);
        float4 y;
        y.x = (v[i].x - mean) * rstd * g.x + bb.x;
        y.y = (v[i].y - mean) * rstd * g.y + bb.y;
        y.z = (v[i].z - mean) * rstd * g.z + bb.z;
        y.w = (v[i].w - mean) * rstd * g.w + bb.w;
        unsigned long long p = (unsigned long long)f2bf(y.x)
            | ((unsigned long long)f2bf(y.y) << 16)
            | ((unsigned long long)f2bf(y.z) << 32)
            | ((unsigned long long)f2bf(y.w) << 48);
        *(unsigned long long*)(yb + ((size_t)row << 10) + off) = p;
    }
}

// ---------------------------------------------------------------------------
// Weight transpose + cast, all three weights in one launch:
// Wall_t rows 0..1023 = Wq^T, 1024..3071 = Wkv^T, 3072..4095 = Wo^T.
// ---------------------------------------------------------------------------
__global__ __launch_bounds__(256) void wt_kernel(
    const float* __restrict__ Wq, const float* __restrict__ Wkv,
    const float* __restrict__ Wo, u16* __restrict__ Wt) {
    int n0 = blockIdx.x << 5;   // 0..4095 (32-aligned; never crosses a source boundary)
    int k0 = blockIdx.y << 5;
    const float* W; int sn0, SN;
    if (n0 < 1024)      { W = Wq;  sn0 = n0;        SN = 1024; }
    else if (n0 < 3072) { W = Wkv; sn0 = n0 - 1024; SN = 2048; }
    else                { W = Wo;  sn0 = n0 - 3072; SN = 1024; }
    __shared__ float tile[32][33];
    int tx = threadIdx.x & 31, ty = threadIdx.x >> 5;  // ty 0..7
#pragma unroll
    for (int r = 0; r < 4; ++r)
        tile[ty + r * 8][tx] = W[(size_t)(k0 + ty + r * 8) * SN + sn0 + tx];
    __syncthreads();
#pragma unroll
    for (int r = 0; r < 4; ++r)
        Wt[(size_t)(n0 + ty + r * 8) * 1024 + k0 + tx] = f2bf(tile[tx][ty + r * 8]);
}

// ---------------------------------------------------------------------------
// V transpose: QKVp V-cols (2048+) -> Vt[(b*16+h)*64 + d][k], key order
// permuted within each 64-block: stored col k' holds key (k'&3)*16 + (k'>>2).
// ---------------------------------------------------------------------------
__global__ __launch_bounds__(256) void vtrans_kernel(
    const u16* __restrict__ QKVp, u16* __restrict__ Vt) {
    int bh = blockIdx.x;          // b*16+h
    int b = bh >> 4, h = bh & 15;
    int kt = blockIdx.y;          // 64-key tile
    int t = threadIdx.x;
    __shared__ u16 tile[64][80];  // [k][d], stride 80 u16 (16B-aligned rows)
    int seg = t & 7;
#pragma unroll
    for (int p = 0; p < 2; ++p) {
        int k = (t >> 3) + (p << 5);
        *(uint4*)&tile[k][seg << 3] =
            *(const uint4*)(QKVp + (size_t)((b << 10) + (kt << 6) + k) * 3072
                            + 2048 + (h << 6) + (seg << 3));
    }
    __syncthreads();
#pragma unroll
    for (int p = 0; p < 2; ++p) {
        int d = (t >> 3) + (p << 5);
        __align__(16) u16 vals[8];
#pragma unroll
        for (int e = 0; e < 8; ++e) {
            int kp = (seg << 3) + e;                 // k' output col
            int ksrc = ((kp & 3) << 4) + (kp >> 2);  // original key
            vals[e] = tile[ksrc][d];
        }
        *(uint4*)(Vt + (size_t)((bh << 6) + d) * 1024 + (kt << 6) + (seg << 3)) =
            *(uint4*)vals;
    }
}

// ---------------------------------------------------------------------------
// GEMM: C[M,N] = A[M,K] @ Bt[N,K]^T + bias (+ scale / + residual).
// Block tile (32*WMT) x 128, 2x2 waves of (16*WMT)x64, 16x16x32 mfma, BK=64.
// WMT=8: 256x128 block tile -> LDS-read bytes/FLOP cut 1.33x vs 128x128
// (wave-tile reuse), keeping the proven zero-conflict 16-row fragment reads.
// MODE 0 (QKV proj): bf16 out; cols<1024 bias bq + scale qscale,
//                    cols>=1024 bias bkv[col-1024].
// MODE 1 (O proj):   fp32 out + bias bq + bf16 residual.
// ---------------------------------------------------------------------------
template <int MODE, int WMT>
__global__ __launch_bounds__(256) void gemm_bt(
    const u16* __restrict__ A, const u16* __restrict__ Bt,
    const float* __restrict__ bq, const float* __restrict__ bkv,
    const u16* __restrict__ resb, float* __restrict__ Cf, u16* __restrict__ Cb,
    int M, int N, int K, float qscale) {
    __shared__ __align__(16) u16 sA[WMT * 32 * 64];
    __shared__ __align__(16) u16 sB[128 * 64];
    int m0 = blockIdx.y * (WMT * 32), n0 = blockIdx.x << 7;
    int tid = threadIdx.x, lane = tid & 63, wave = tid >> 6;
    int quad = lane >> 4, l15 = lane & 15, swr = lane & 7;
    int wm = (wave >> 1) * (WMT * 16), wn = (wave & 1) << 6;
    int srow = lane >> 3;
    int gseg = (lane & 7) ^ srow;

    fx4 acc[WMT][4];
    fx4 zero = {0.0f, 0.0f, 0.0f, 0.0f};
#pragma unroll
    for (int i = 0; i < WMT; ++i)
#pragma unroll
        for (int j = 0; j < 4; ++j) acc[i][j] = zero;

    for (int k0 = 0; k0 < K; k0 += 64) {
#pragma unroll
        for (int t = 0; t < WMT; ++t) {
            int cA = wave * WMT + t;          // A chunk 0..4*WMT-1
            int rowA = (cA << 3) + srow;
            gload_lds16(A + (size_t)(m0 + rowA) * K + k0 + (gseg << 3), &sA[cA << 9]);
            if (t < 4) {
                int cB = (wave << 2) + t;     // B chunk 0..15
                int rowB = (cB << 3) + srow;
                gload_lds16(Bt + (size_t)(n0 + rowB) * K + k0 + (gseg << 3), &sB[cB << 9]);
            }
        }
        __syncthreads();
#pragma unroll
        for (int kk = 0; kk < 64; kk += 32) {
            int ks = (kk >> 3) + quad;
            short8 af[WMT], bf[4];
#pragma unroll
            for (int mt = 0; mt < WMT; ++mt) {
                int r = wm + (mt << 4) + l15;
                af[mt] = *(const short8*)&sA[(r << 6) + (((ks ^ swr) & 7) << 3)];
            }
#pragma unroll
            for (int nt = 0; nt < 4; ++nt) {
                int r = wn + (nt << 4) + l15;
                bf[nt] = *(const short8*)&sB[(r << 6) + (((ks ^ swr) & 7) << 3)];
            }
#pragma unroll
            for (int mt = 0; mt < WMT; ++mt)
#pragma unroll
                for (int nt = 0; nt < 4; ++nt)
                    acc[mt][nt] = mfma16(af[mt], bf[nt], acc[mt][nt]);
        }
        __syncthreads();
    }

#pragma unroll
    for (int mt = 0; mt < WMT; ++mt)
#pragma unroll
        for (int nt = 0; nt < 4; ++nt)
#pragma unroll
            for (int r = 0; r < 4; ++r) {
                int row = m0 + wm + (mt << 4) + (quad << 2) + r;
                int col = n0 + wn + (nt << 4) + l15;
                if (MODE == 1) {
                    float v = acc[mt][nt][r] + bq[col];
                    size_t idx = (size_t)row * N + col;
                    Cf[idx] = v + bf2f(resb[idx]);
                } else {
                    float bias = (col < 1024) ? bq[col] : bkv[col - 1024];
                    float v = acc[mt][nt][r] + bias;
                    if (col < 1024) v *= qscale;
                    Cb[(size_t)row * N + col] = f2bf(v);
                }
            }
}

// ---------------------------------------------------------------------------
// Flash attention, no-max softmax (scores bounded; scale+log2e folded into Q
// by the projection epilogue).  QKVp: [8192][3072] bf16, Q cols 0..1023
// (pre-scaled), K cols 1024..2047.  Vt: [bh*64+d][k'] (key-permuted).
// Block: 4 waves x 32 q-rows = 128-row strip; each block does strips j, 7-j.
// ---------------------------------------------------------------------------
__global__ __launch_bounds__(256) void attn_kernel(
    const u16* __restrict__ QKVp, const u16* __restrict__ Vt,
    const int* __restrict__ lens, u16* __restrict__ O) {
    int bh = blockIdx.x;
    int b = bh >> 4, h = bh & 15;
    int j = blockIdx.y;          // strip pair: j and 7-j
    int len = lens[b];
    int cap = (len - 1) >> 6;    // last key tile with any valid key
    int tid = threadIdx.x, lane = tid & 63, w = tid >> 6;
    int quad = lane >> 4, l15 = lane & 15;

    __shared__ __align__(16) u16 sK[64 * 64];   // [key][d], seg-swizzled
    __shared__ __align__(16) u16 sV[64 * 64];   // [d][k'],  seg-swizzled
    __shared__ __align__(16) u16 sP[4 * 2048];  // per-wave 32x64 bf16 P
    u16* sPw = &sP[w << 11];

    int lrow = lane >> 3;       // 0..7: row within an 8-row staging chunk
    int lseg = lane & 7;

    fx4 zero = {0.0f, 0.0f, 0.0f, 0.0f};

#pragma unroll
    for (int phase = 0; phase < 2; ++phase) {
        int s = phase ? (7 - j) : j;
        int q0 = s << 7;
        int wq0 = q0 + (w << 5);
        int ktend_blk = min((q0 + 127) >> 6, cap);
        int ktend_w   = min((wq0 + 31) >> 6, cap);

        // Q fragments in registers for the whole strip
        short8 qf[2][2];
#pragma unroll
        for (int mt = 0; mt < 2; ++mt)
#pragma unroll
            for (int kk = 0; kk < 2; ++kk) {
                int qrow = (b << 10) + wq0 + (mt << 4) + l15;
                qf[mt][kk] = *(const short8*)(QKVp + (size_t)qrow * 3072
                              + (h << 6) + (kk << 5) + (quad << 3));
            }

        fx4 oacc[2][4];
        float lsum[2][4];
#pragma unroll
        for (int mt = 0; mt < 2; ++mt)
#pragma unroll
            for (int nt = 0; nt < 4; ++nt) oacc[mt][nt] = zero;
#pragma unroll
        for (int mt = 0; mt < 2; ++mt)
#pragma unroll
            for (int r = 0; r < 4; ++r) lsum[mt][r] = 0.0f;

        for (int kt = 0; kt <= ktend_blk; ++kt) {
            int k0g = kt << 6;
            // --- stage K and Vt tiles (async, direct-to-LDS) ---
#pragma unroll
            for (int i = 0; i < 2; ++i) {
                int row = (w << 4) + (i << 3) + lrow;      // key row / d row
                int gs = lseg ^ (row & 7);
                gload_lds16(QKVp + (size_t)((b << 10) + k0g + row) * 3072
                               + 1024 + (h << 6) + (gs << 3),
                            &sK[((w << 1) + i) << 9]);
                gload_lds16(Vt + (size_t)((bh << 6) + row) * 1024
                               + k0g + (gs << 3),
                            &sV[((w << 1) + i) << 9]);
            }
            __syncthreads();   // drains vmcnt -> staged data visible

            if (kt <= ktend_w) {
                // --- S = Q K^T ---
                fx4 sacc[2][4];
#pragma unroll
                for (int mt = 0; mt < 2; ++mt)
#pragma unroll
                    for (int nt = 0; nt < 4; ++nt) sacc[mt][nt] = zero;
#pragma unroll
                for (int kk = 0; kk < 2; ++kk) {
                    int seg = (kk << 2) + quad;
                    short8 kf[4];
#pragma unroll
                    for (int nt = 0; nt < 4; ++nt) {
                        int row = (nt << 4) + l15;
                        kf[nt] = *(const short8*)&sK[(row << 6)
                                   + (((seg ^ (row & 7)) & 7) << 3)];
                    }
#pragma unroll
                    for (int mt = 0; mt < 2; ++mt)
#pragma unroll
                        for (int nt = 0; nt < 4; ++nt)
                            sacc[mt][nt] = mfma16(qf[mt][kk], kf[nt], sacc[mt][nt]);
                }

                // --- masks (boundary tiles only) ---
                bool needm = ((k0g + 63) > wq0) || ((k0g + 64) > len);
                if (needm) {
#pragma unroll
                    for (int mt = 0; mt < 2; ++mt)
#pragma unroll
                        for (int nt = 0; nt < 4; ++nt) {
                            int kg = k0g + (nt << 4) + l15;
#pragma unroll
                            for (int r = 0; r < 4; ++r) {
                                int qr = wq0 + (mt << 4) + (quad << 2) + r;
                                if (kg > qr || kg >= len)
                                    sacc[mt][nt][r] = -30000.0f;
                            }
                        }
                }

                // --- p = exp2(s), accumulate l, pack P to LDS ---
#pragma unroll
                for (int mt = 0; mt < 2; ++mt) {
#pragma unroll
                    for (int nt = 0; nt < 4; ++nt)
#pragma unroll
                        for (int r = 0; r < 4; ++r)
                            sacc[mt][nt][r] = fast_exp2(sacc[mt][nt][r]);
#pragma unroll
                    for (int r = 0; r < 4; ++r) {
                        lsum[mt][r] += (sacc[mt][0][r] + sacc[mt][1][r])
                                     + (sacc[mt][2][r] + sacc[mt][3][r]);
                        int row = (mt << 4) + (quad << 2) + r;
                        u32 lo = pack_bf2(sacc[mt][0][r], sacc[mt][1][r]);
                        u32 hi = pack_bf2(sacc[mt][2][r], sacc[mt][3][r]);
                        uint2 pv; pv.x = lo; pv.y = hi;
                        int addr = (row << 6)
                                 + (((((l15 >> 1)) ^ (row & 7)) & 7) << 3)
                                 + ((l15 & 1) << 2);
                        *(uint2*)&sPw[addr] = pv;
                    }
                }
                // sP is wave-private -> only need LDS-op completion, no barrier
                __builtin_amdgcn_s_waitcnt(0xC07F);  // lgkmcnt(0)

                // --- O += P V ---
#pragma unroll
                for (int kk = 0; kk < 2; ++kk) {
                    int seg = (kk << 2) + quad;
                    short8 vf[4], pf[2];
#pragma unroll
                    for (int nt = 0; nt < 4; ++nt) {
                        int row = (nt << 4) + l15;
                        vf[nt] = *(const short8*)&sV[(row << 6)
                                   + (((seg ^ (row & 7)) & 7) << 3)];
                    }
#pragma unroll
                    for (int mt = 0; mt < 2; ++mt) {
                        int row = (mt << 4) + l15;
                        pf[mt] = *(const short8*)&sPw[(row << 6)
                                   + (((seg ^ (row & 7)) & 7) << 3)];
                    }
#pragma unroll
                    for (int mt = 0; mt < 2; ++mt)
#pragma unroll
                        for (int nt = 0; nt < 4; ++nt)
                            oacc[mt][nt] = mfma16(pf[mt], vf[nt], oacc[mt][nt]);
                }
            }
            __syncthreads();   // protect sK/sV for next tile's staging
        }

        // --- reduce l across the 16 lanes of each quad, normalize, write ---
#pragma unroll
        for (int mt = 0; mt < 2; ++mt)
#pragma unroll
            for (int r = 0; r < 4; ++r) {
                float v = lsum[mt][r];
                v += __shfl_xor(v, 1, 64);
                v += __shfl_xor(v, 2, 64);
                v += __shfl_xor(v, 4, 64);
                v += __shfl_xor(v, 8, 64);
                lsum[mt][r] = __builtin_amdgcn_rcpf(v);
            }
#pragma unroll
        for (int mt = 0; mt < 2; ++mt)
#pragma unroll
            for (int nt = 0; nt < 4; ++nt)
#pragma unroll
                for (int r = 0; r < 4; ++r) {
                    int row = (b << 10) + wq0 + (mt << 4) + (quad << 2) + r;
                    int col = (h << 6) + (nt << 4) + l15;
                    O[((size_t)row << 10) + col] =
                        f2bf(oacc[mt][nt][r] * lsum[mt][r]);
                }
    }
}

// ---------------------------------------------------------------------------
extern "C" void kernel_launch(void* const* d_in, const int* in_sizes, int n_in,
                              void* d_out, int out_size, void* d_ws, size_t ws_size,
                              hipStream_t stream) {
    (void)in_sizes; (void)n_in; (void)out_size; (void)ws_size;
    const float* x    = (const float*)d_in[0];
    const int*   lens = (const int*)d_in[2];
    const float* Wq   = (const float*)d_in[3];
    const float* bq   = (const float*)d_in[4];
    const float* Wkv  = (const float*)d_in[5];
    const float* bkv  = (const float*)d_in[6];
    const float* Wo   = (const float*)d_in[7];
    const float* bo   = (const float*)d_in[8];
    const float* gam  = (const float*)d_in[9];
    const float* bet  = (const float*)d_in[10];
    float* out = (float*)d_out;

    char* w = (char*)d_ws;
    u16* xln_b  = (u16*)w;  w += (size_t)8192 * 1024 * 2;   // 16 MB: LN out (GEMM A + bf16 residual)
    u16* Wall_t = (u16*)w;  w += (size_t)4096 * 1024 * 2;   //  8 MB: [Wq^T | Wkv^T | Wo^T]
    u16* QKVp   = (u16*)w;  w += (size_t)8192 * 3072 * 2;   // 48 MB: Q(scaled)|K|V
    u16* Vt     = (u16*)w;  w += (size_t)8192 * 1024 * 2;   // 16 MB: V transposed + key-permuted
    u16* AO     = (u16*)w;  w += (size_t)8192 * 1024 * 2;   // 16 MB: attention out
    // total 104 MB

    ln_kernel<<<2048, 256, 0, stream>>>(x, gam, bet, xln_b);
    wt_kernel<<<dim3(128, 32), 256, 0, stream>>>(Wq, Wkv, Wo, Wall_t);
    gemm_bt<0, 8><<<dim3(24, 32), 256, 0, stream>>>(xln_b, Wall_t, bq, bkv,
        nullptr, nullptr, QKVp, 8192, 3072, 1024, 0.125f * LOG2E);
    vtrans_kernel<<<dim3(128, 16), 256, 0, stream>>>(QKVp, Vt);
    attn_kernel<<<dim3(128, 4), 256, 0, stream>>>(QKVp, Vt, lens, AO);
    gemm_bt<1, 8><<<dim3(8, 32), 256, 0, stream>>>(AO, Wall_t + (size_t)3072 * 1024,
        bo, nullptr, xln_b, out, nullptr, 8192, 1024, 1024, 1.0f);
}

// Round 5
// 262.503 us; speedup vs baseline: 1.1526x; 1.1526x over previous
//
#include <hip/hip_runtime.h>

typedef unsigned short u16;
typedef unsigned int u32;
typedef __attribute__((ext_vector_type(8))) short short8;
typedef __attribute__((ext_vector_type(4))) float fx4;

#define LOG2E 1.44269504088896340736f

__device__ __forceinline__ u16 f2bf(float f) {
    unsigned int u = __float_as_uint(f);
    u += 0x7fffu + ((u >> 16) & 1u);
    return (u16)(u >> 16);
}

__device__ __forceinline__ float bf2f(u16 v) {
    u32 u = ((u32)v) << 16;
    return __uint_as_float(u);
}

// pack two fp32 -> two truncated bf16 in one u32 (v_perm_b32)
__device__ __forceinline__ u32 pack_bf2(float lo, float hi) {
    return __builtin_amdgcn_perm(__float_as_uint(hi), __float_as_uint(lo), 0x07060302u);
}

__device__ __forceinline__ float fast_exp2(float x) {
#if __has_builtin(__builtin_amdgcn_exp2f)
    return __builtin_amdgcn_exp2f(x);
#else
    return exp2f(x);
#endif
}

__device__ __forceinline__ fx4 mfma16(short8 a, short8 b, fx4 c) {
    return __builtin_amdgcn_mfma_f32_16x16x32_bf16(a, b, c, 0, 0, 0);
}

__device__ __forceinline__ void gload_lds16(const u16* g, u16* l) {
    __builtin_amdgcn_global_load_lds(
        (const __attribute__((address_space(1))) void*)g,
        (__attribute__((address_space(3))) void*)l, 16, 0, 0);
}

// ---------------------------------------------------------------------------
// Fused LayerNorm + weight transpose (heterogeneous grid, 6144 blocks):
//   blocks 0..2047:   LN, 4 rows each (one wave per row, shuffle-only).
//   blocks 2048..6143: 32x32 transpose tiles of [Wq|Wkv|Wo] -> Wall_t.
// ---------------------------------------------------------------------------
__global__ __launch_bounds__(256) void ln_wt_kernel(
    const float* __restrict__ x, const float* __restrict__ gamma,
    const float* __restrict__ beta, u16* __restrict__ yb,
    const float* __restrict__ Wq, const float* __restrict__ Wkv,
    const float* __restrict__ Wo, u16* __restrict__ Wt) {
    int blk = blockIdx.x;
    if (blk < 2048) {
        int wave = threadIdx.x >> 6, lane = threadIdx.x & 63;
        int row = (blk << 2) + wave;
        const float* xr = x + ((size_t)row << 10);
        float4 v[4];
        float s = 0.0f, sq = 0.0f;
#pragma unroll
        for (int i = 0; i < 4; ++i) {
            v[i] = *(const float4*)(xr + (i << 8) + (lane << 2));
            s  += v[i].x + v[i].y + v[i].z + v[i].w;
            sq += v[i].x * v[i].x + v[i].y * v[i].y + v[i].z * v[i].z + v[i].w * v[i].w;
        }
#pragma unroll
        for (int o = 32; o > 0; o >>= 1) {
            s  += __shfl_xor(s, o, 64);
            sq += __shfl_xor(sq, o, 64);
        }
        float mean = s * (1.0f / 1024.0f);
        float var  = sq * (1.0f / 1024.0f) - mean * mean;
        float rstd = rsqrtf(var + 1e-3f);
#pragma unroll
        for (int i = 0; i < 4; ++i) {
            int off = (i << 8) + (lane << 2);
            float4 g  = *(const float4*)(gamma + off);
            float4 bb = *(const float4*)(beta + off);
            float4 y;
            y.x = (v[i].x - mean) * rstd * g.x + bb.x;
            y.y = (v[i].y - mean) * rstd * g.y + bb.y;
            y.z = (v[i].z - mean) * rstd * g.z + bb.z;
            y.w = (v[i].w - mean) * rstd * g.w + bb.w;
            unsigned long long p = (unsigned long long)f2bf(y.x)
                | ((unsigned long long)f2bf(y.y) << 16)
                | ((unsigned long long)f2bf(y.z) << 32)
                | ((unsigned long long)f2bf(y.w) << 48);
            *(unsigned long long*)(yb + ((size_t)row << 10) + off) = p;
        }
    } else {
        int wtb = blk - 2048;
        int n0 = (wtb & 127) << 5;   // 0..4095
        int k0 = (wtb >> 7) << 5;    // 0..1023
        const float* W; int sn0, SN;
        if (n0 < 1024)      { W = Wq;  sn0 = n0;        SN = 1024; }
        else if (n0 < 3072) { W = Wkv; sn0 = n0 - 1024; SN = 2048; }
        else                { W = Wo;  sn0 = n0 - 3072; SN = 1024; }
        __shared__ float tile[32][33];
        int tx = threadIdx.x & 31, ty = threadIdx.x >> 5;  // ty 0..7
#pragma unroll
        for (int r = 0; r < 4; ++r)
            tile[ty + r * 8][tx] = W[(size_t)(k0 + ty + r * 8) * SN + sn0 + tx];
        __syncthreads();
#pragma unroll
        for (int r = 0; r < 4; ++r)
            Wt[(size_t)(n0 + ty + r * 8) * 1024 + k0 + tx] = f2bf(tile[tx][ty + r * 8]);
    }
}

// ---------------------------------------------------------------------------
// GEMM: C[M,N] = A[M,K] @ Bt[N,K]^T + bias.  128x128 block tile (WMT=4),
// 2x2 waves of 64x64, 16x16x32 mfma, BK=64, global_load_lds w16 staging,
// XOR-swizzled LDS (zero-conflict 16-row fragment reads).
// MODE 0 (QKV proj): cols<1024 -> bf16 QKVp with bias bq, scale qscale;
//                    1024<=col<2048 -> bf16 QKVp with bias bkv (K part);
//                    col>=2048 -> V: written DIRECTLY to Vt transposed with
//                    the k' permutation (k' = 4*(k&15) + (k>>4)) - fused
//                    vtrans.  QKVp V-cols are never written.
// MODE 1 (O proj):   fp32 out + bias bq + bf16 residual.
// ---------------------------------------------------------------------------
template <int MODE, int WMT>
__global__ __launch_bounds__(256) void gemm_bt(
    const u16* __restrict__ A, const u16* __restrict__ Bt,
    const float* __restrict__ bq, const float* __restrict__ bkv,
    const u16* __restrict__ resb, float* __restrict__ Cf, u16* __restrict__ Cb,
    u16* __restrict__ Vt, int M, int N, int K, float qscale) {
    __shared__ __align__(16) u16 sA[WMT * 32 * 64];
    __shared__ __align__(16) u16 sB[128 * 64];
    int m0 = blockIdx.y * (WMT * 32), n0 = blockIdx.x << 7;
    int tid = threadIdx.x, lane = tid & 63, wave = tid >> 6;
    int quad = lane >> 4, l15 = lane & 15, swr = lane & 7;
    int wm = (wave >> 1) * (WMT * 16), wn = (wave & 1) << 6;
    int srow = lane >> 3;
    int gseg = (lane & 7) ^ srow;

    fx4 acc[WMT][4];
    fx4 zero = {0.0f, 0.0f, 0.0f, 0.0f};
#pragma unroll
    for (int i = 0; i < WMT; ++i)
#pragma unroll
        for (int j = 0; j < 4; ++j) acc[i][j] = zero;

    for (int k0 = 0; k0 < K; k0 += 64) {
#pragma unroll
        for (int t = 0; t < WMT; ++t) {
            int cA = wave * WMT + t;
            int rowA = (cA << 3) + srow;
            gload_lds16(A + (size_t)(m0 + rowA) * K + k0 + (gseg << 3), &sA[cA << 9]);
            if (t < 4) {
                int cB = (wave << 2) + t;
                int rowB = (cB << 3) + srow;
                gload_lds16(Bt + (size_t)(n0 + rowB) * K + k0 + (gseg << 3), &sB[cB << 9]);
            }
        }
        __syncthreads();
#pragma unroll
        for (int kk = 0; kk < 64; kk += 32) {
            int ks = (kk >> 3) + quad;
            short8 af[WMT], bf[4];
#pragma unroll
            for (int mt = 0; mt < WMT; ++mt) {
                int r = wm + (mt << 4) + l15;
                af[mt] = *(const short8*)&sA[(r << 6) + (((ks ^ swr) & 7) << 3)];
            }
#pragma unroll
            for (int nt = 0; nt < 4; ++nt) {
                int r = wn + (nt << 4) + l15;
                bf[nt] = *(const short8*)&sB[(r << 6) + (((ks ^ swr) & 7) << 3)];
            }
#pragma unroll
            for (int mt = 0; mt < WMT; ++mt)
#pragma unroll
                for (int nt = 0; nt < 4; ++nt)
                    acc[mt][nt] = mfma16(af[mt], bf[nt], acc[mt][nt]);
        }
        __syncthreads();
    }

    if (MODE == 0 && n0 >= 2048) {
        // --- V region: fused transpose+permute into Vt ---
#pragma unroll
        for (int mt = 0; mt < WMT; ++mt)
#pragma unroll
            for (int nt = 0; nt < 4; ++nt)
#pragma unroll
                for (int r = 0; r < 4; ++r) {
                    int row = m0 + wm + (mt << 4) + (quad << 2) + r;
                    int col = n0 + wn + (nt << 4) + l15;
                    float v = acc[mt][nt][r] + bkv[col - 1024];
                    int bb = row >> 10, k = row & 1023;
                    int h = (col - 2048) >> 6, d = col & 63;
                    int kt = k >> 6, kin = k & 63;
                    int kp = ((kin & 15) << 2) | (kin >> 4);
                    Vt[(size_t)((((bb << 4) + h) << 6) + d) * 1024
                       + (kt << 6) + kp] = f2bf(v);
                }
        return;
    }

#pragma unroll
    for (int mt = 0; mt < WMT; ++mt)
#pragma unroll
        for (int nt = 0; nt < 4; ++nt)
#pragma unroll
            for (int r = 0; r < 4; ++r) {
                int row = m0 + wm + (mt << 4) + (quad << 2) + r;
                int col = n0 + wn + (nt << 4) + l15;
                if (MODE == 1) {
                    float v = acc[mt][nt][r] + bq[col];
                    size_t idx = (size_t)row * N + col;
                    Cf[idx] = v + bf2f(resb[idx]);
                } else {
                    float bias = (col < 1024) ? bq[col] : bkv[col - 1024];
                    float v = acc[mt][nt][r] + bias;
                    if (col < 1024) v *= qscale;
                    Cb[(size_t)row * N + col] = f2bf(v);
                }
            }
}

// ---------------------------------------------------------------------------
// Flash attention, no-max softmax (scores bounded; scale+log2e folded into Q
// by the projection epilogue).  QKVp: [8192][3072] bf16, Q cols 0..1023
// (pre-scaled), K cols 1024..2047.  Vt: [bh*64+d][k'] (key-permuted).
// Block: 4 waves x 32 q-rows = 128-row strip; each block does strips j, 7-j.
// ---------------------------------------------------------------------------
__global__ __launch_bounds__(256) void attn_kernel(
    const u16* __restrict__ QKVp, const u16* __restrict__ Vt,
    const int* __restrict__ lens, u16* __restrict__ O) {
    int bh = blockIdx.x;
    int b = bh >> 4, h = bh & 15;
    int j = blockIdx.y;          // strip pair: j and 7-j
    int len = lens[b];
    int cap = (len - 1) >> 6;    // last key tile with any valid key
    int tid = threadIdx.x, lane = tid & 63, w = tid >> 6;
    int quad = lane >> 4, l15 = lane & 15;

    __shared__ __align__(16) u16 sK[64 * 64];   // [key][d], seg-swizzled
    __shared__ __align__(16) u16 sV[64 * 64];   // [d][k'],  seg-swizzled
    __shared__ __align__(16) u16 sP[4 * 2048];  // per-wave 32x64 bf16 P
    u16* sPw = &sP[w << 11];

    int lrow = lane >> 3;       // 0..7: row within an 8-row staging chunk
    int lseg = lane & 7;

    fx4 zero = {0.0f, 0.0f, 0.0f, 0.0f};

#pragma unroll
    for (int phase = 0; phase < 2; ++phase) {
        int s = phase ? (7 - j) : j;
        int q0 = s << 7;
        int wq0 = q0 + (w << 5);
        int ktend_blk = min((q0 + 127) >> 6, cap);
        int ktend_w   = min((wq0 + 31) >> 6, cap);

        // Q fragments in registers for the whole strip
        short8 qf[2][2];
#pragma unroll
        for (int mt = 0; mt < 2; ++mt)
#pragma unroll
            for (int kk = 0; kk < 2; ++kk) {
                int qrow = (b << 10) + wq0 + (mt << 4) + l15;
                qf[mt][kk] = *(const short8*)(QKVp + (size_t)qrow * 3072
                              + (h << 6) + (kk << 5) + (quad << 3));
            }

        fx4 oacc[2][4];
        float lsum[2][4];
#pragma unroll
        for (int mt = 0; mt < 2; ++mt)
#pragma unroll
            for (int nt = 0; nt < 4; ++nt) oacc[mt][nt] = zero;
#pragma unroll
        for (int mt = 0; mt < 2; ++mt)
#pragma unroll
            for (int r = 0; r < 4; ++r) lsum[mt][r] = 0.0f;

        for (int kt = 0; kt <= ktend_blk; ++kt) {
            int k0g = kt << 6;
            // --- stage K and Vt tiles (async, direct-to-LDS) ---
#pragma unroll
            for (int i = 0; i < 2; ++i) {
                int row = (w << 4) + (i << 3) + lrow;      // key row / d row
                int gs = lseg ^ (row & 7);
                gload_lds16(QKVp + (size_t)((b << 10) + k0g + row) * 3072
                               + 1024 + (h << 6) + (gs << 3),
                            &sK[((w << 1) + i) << 9]);
                gload_lds16(Vt + (size_t)((bh << 6) + row) * 1024
                               + k0g + (gs << 3),
                            &sV[((w << 1) + i) << 9]);
            }
            __syncthreads();   // drains vmcnt -> staged data visible

            if (kt <= ktend_w) {
                // --- S = Q K^T ---
                fx4 sacc[2][4];
#pragma unroll
                for (int mt = 0; mt < 2; ++mt)
#pragma unroll
                    for (int nt = 0; nt < 4; ++nt) sacc[mt][nt] = zero;
#pragma unroll
                for (int kk = 0; kk < 2; ++kk) {
                    int seg = (kk << 2) + quad;
                    short8 kf[4];
#pragma unroll
                    for (int nt = 0; nt < 4; ++nt) {
                        int row = (nt << 4) + l15;
                        kf[nt] = *(const short8*)&sK[(row << 6)
                                   + (((seg ^ (row & 7)) & 7) << 3)];
                    }
#pragma unroll
                    for (int mt = 0; mt < 2; ++mt)
#pragma unroll
                        for (int nt = 0; nt < 4; ++nt)
                            sacc[mt][nt] = mfma16(qf[mt][kk], kf[nt], sacc[mt][nt]);
                }

                // --- masks (boundary tiles only) ---
                bool needm = ((k0g + 63) > wq0) || ((k0g + 64) > len);
                if (needm) {
#pragma unroll
                    for (int mt = 0; mt < 2; ++mt)
#pragma unroll
                        for (int nt = 0; nt < 4; ++nt) {
                            int kg = k0g + (nt << 4) + l15;
#pragma unroll
                            for (int r = 0; r < 4; ++r) {
                                int qr = wq0 + (mt << 4) + (quad << 2) + r;
                                if (kg > qr || kg >= len)
                                    sacc[mt][nt][r] = -30000.0f;
                            }
                        }
                }

                // --- p = exp2(s), accumulate l, pack P to LDS ---
#pragma unroll
                for (int mt = 0; mt < 2; ++mt) {
#pragma unroll
                    for (int nt = 0; nt < 4; ++nt)
#pragma unroll
                        for (int r = 0; r < 4; ++r)
                            sacc[mt][nt][r] = fast_exp2(sacc[mt][nt][r]);
#pragma unroll
                    for (int r = 0; r < 4; ++r) {
                        lsum[mt][r] += (sacc[mt][0][r] + sacc[mt][1][r])
                                     + (sacc[mt][2][r] + sacc[mt][3][r]);
                        int row = (mt << 4) + (quad << 2) + r;
                        u32 lo = pack_bf2(sacc[mt][0][r], sacc[mt][1][r]);
                        u32 hi = pack_bf2(sacc[mt][2][r], sacc[mt][3][r]);
                        uint2 pv; pv.x = lo; pv.y = hi;
                        int addr = (row << 6)
                                 + (((((l15 >> 1)) ^ (row & 7)) & 7) << 3)
                                 + ((l15 & 1) << 2);
                        *(uint2*)&sPw[addr] = pv;
                    }
                }
                // sP is wave-private -> only need LDS-op completion, no barrier
                __builtin_amdgcn_s_waitcnt(0xC07F);  // lgkmcnt(0)

                // --- O += P V ---
#pragma unroll
                for (int kk = 0; kk < 2; ++kk) {
                    int seg = (kk << 2) + quad;
                    short8 vf[4], pf[2];
#pragma unroll
                    for (int nt = 0; nt < 4; ++nt) {
                        int row = (nt << 4) + l15;
                        vf[nt] = *(const short8*)&sV[(row << 6)
                                   + (((seg ^ (row & 7)) & 7) << 3)];
                    }
#pragma unroll
                    for (int mt = 0; mt < 2; ++mt) {
                        int row = (mt << 4) + l15;
                        pf[mt] = *(const short8*)&sPw[(row << 6)
                                   + (((seg ^ (row & 7)) & 7) << 3)];
                    }
#pragma unroll
                    for (int mt = 0; mt < 2; ++mt)
#pragma unroll
                        for (int nt = 0; nt < 4; ++nt)
                            oacc[mt][nt] = mfma16(pf[mt], vf[nt], oacc[mt][nt]);
                }
            }
            __syncthreads();   // protect sK/sV for next tile's staging
        }

        // --- reduce l across the 16 lanes of each quad, normalize, write ---
#pragma unroll
        for (int mt = 0; mt < 2; ++mt)
#pragma unroll
            for (int r = 0; r < 4; ++r) {
                float v = lsum[mt][r];
                v += __shfl_xor(v, 1, 64);
                v += __shfl_xor(v, 2, 64);
                v += __shfl_xor(v, 4, 64);
                v += __shfl_xor(v, 8, 64);
                lsum[mt][r] = __builtin_amdgcn_rcpf(v);
            }
#pragma unroll
        for (int mt = 0; mt < 2; ++mt)
#pragma unroll
            for (int nt = 0; nt < 4; ++nt)
#pragma unroll
                for (int r = 0; r < 4; ++r) {
                    int row = (b << 10) + wq0 + (mt << 4) + (quad << 2) + r;
                    int col = (h << 6) + (nt << 4) + l15;
                    O[((size_t)row << 10) + col] =
                        f2bf(oacc[mt][nt][r] * lsum[mt][r]);
                }
    }
}

// ---------------------------------------------------------------------------
extern "C" void kernel_launch(void* const* d_in, const int* in_sizes, int n_in,
                              void* d_out, int out_size, void* d_ws, size_t ws_size,
                              hipStream_t stream) {
    (void)in_sizes; (void)n_in; (void)out_size; (void)ws_size;
    const float* x    = (const float*)d_in[0];
    const int*   lens = (const int*)d_in[2];
    const float* Wq   = (const float*)d_in[3];
    const float* bq   = (const float*)d_in[4];
    const float* Wkv  = (const float*)d_in[5];
    const float* bkv  = (const float*)d_in[6];
    const float* Wo   = (const float*)d_in[7];
    const float* bo   = (const float*)d_in[8];
    const float* gam  = (const float*)d_in[9];
    const float* bet  = (const float*)d_in[10];
    float* out = (float*)d_out;

    char* w = (char*)d_ws;
    u16* xln_b  = (u16*)w;  w += (size_t)8192 * 1024 * 2;   // 16 MB: LN out (GEMM A + bf16 residual)
    u16* Wall_t = (u16*)w;  w += (size_t)4096 * 1024 * 2;   //  8 MB: [Wq^T | Wkv^T | Wo^T]
    u16* QKVp   = (u16*)w;  w += (size_t)8192 * 3072 * 2;   // 48 MB: Q(scaled)|K (V cols unused)
    u16* Vt     = (u16*)w;  w += (size_t)8192 * 1024 * 2;   // 16 MB: V transposed + key-permuted
    u16* AO     = (u16*)w;  w += (size_t)8192 * 1024 * 2;   // 16 MB: attention out
    // total 104 MB

    ln_wt_kernel<<<6144, 256, 0, stream>>>(x, gam, bet, xln_b, Wq, Wkv, Wo, Wall_t);
    gemm_bt<0, 4><<<dim3(24, 64), 256, 0, stream>>>(xln_b, Wall_t, bq, bkv,
        nullptr, nullptr, QKVp, Vt, 8192, 3072, 1024, 0.125f * LOG2E);
    attn_kernel<<<dim3(128, 4), 256, 0, stream>>>(QKVp, Vt, lens, AO);
    gemm_bt<1, 4><<<dim3(8, 64), 256, 0, stream>>>(AO, Wall_t + (size_t)3072 * 1024,
        bo, nullptr, xln_b, out, nullptr, nullptr, 8192, 1024, 1024, 1.0f);
}